// Round 15
// baseline (119.453 us; speedup 1.0000x reference)
//
#include <hip/hip_runtime.h>

#define NEGV -1e30f

// Problem constants (fixed by setup_inputs)
constexpr int Bn = 8, Ci = 64, Hn = 64, Wn = 64, Co = 64;
constexpr int WT_ELEMS = Ci * 9 * Co;   // 36864
constexpr int HW = Hn * Wn;

typedef float v2f __attribute__((ext_vector_type(2)));

// ---- pre-pass: wT[ci][k][co] = wt[co][ci][k] (147456 B in d_ws) ----
__global__ __launch_bounds__(256)
void wtrans_kernel(const float* __restrict__ wt, float* __restrict__ wT) {
    int idx = blockIdx.x * 256 + threadIdx.x;
    if (idx < WT_ELEMS) {
        int co = idx & 63;
        int k  = (idx >> 6) % 9;
        int ci = idx / 576;
        wT[idx] = wt[((size_t)co * Ci + ci) * 9 + k];
    }
}

__device__ __forceinline__ float vmax3(float a, float b, float c) {
    float d;
    asm("v_max3_f32 %0, %1, %2, %3" : "=v"(d) : "v"(a), "v"(b), "v"(c));
    return d;
}

// uniform LDS window read: 10 floats as 5 even-aligned v2f pairs
// (ds_read_b128 -> pairs {0,1}{2,3}; b128 -> {4,5}{6,7}; b64 -> {8,9})
__device__ __forceinline__ void read10v(v2f* r, const float* __restrict__ p) {
    float4 a = *reinterpret_cast<const float4*>(p);
    float4 b = *reinterpret_cast<const float4*>(p + 4);
    float2 c = *reinterpret_cast<const float2*>(p + 8);
    r[0] = (v2f){a.x, a.y}; r[1] = (v2f){a.z, a.w};
    r[2] = (v2f){b.x, b.y}; r[3] = (v2f){b.z, b.w};
    r[4] = (v2f){c.x, c.y};
}

// Packed core for one out-row from window rows A,B,C (v2f[5] each):
// per px-pair: left/right columns via v_pk_add_f32 (even-aligned pairs),
// middle column via 2 scalar adds; maxes stay scalar (no pk f32 max).
// 6 pk + 6 add + 10 max per pair = 22 instrs for 2 px (vs 28 scalar).
__device__ __forceinline__ void compute8pk(float* acc, const v2f* A,
                                           const v2f* B, const v2f* C,
                                           const float* wv, const v2f* ws) {
#pragma unroll
    for (int q = 0; q < 4; q++) {
        v2f a0 = A[q] + ws[0];           // {x[2q],x[2q+1]} + w0
        v2f a2 = A[q + 1] + ws[1];       // {x[2q+2],x[2q+3]} + w2
        float a1x = A[q].y + wv[1];      // center, px 2q
        float a1y = A[q + 1].x + wv[1];  // center, px 2q+1
        v2f b0 = B[q] + ws[2];
        v2f b2 = B[q + 1] + ws[3];
        float b1x = B[q].y + wv[4];
        float b1y = B[q + 1].x + wv[4];
        v2f c0 = C[q] + ws[4];
        v2f c2 = C[q + 1] + ws[5];
        float c1x = C[q].y + wv[7];
        float c1y = C[q + 1].x + wv[7];
        // pixel 2q
        float m0 = vmax3(a0.x, a1x, a2.x);
        float m1 = vmax3(b0.x, b1x, b2.x);
        float m2 = vmax3(c0.x, c1x, c2.x);
        float t  = vmax3(acc[2 * q], m0, m1);
        acc[2 * q] = fmaxf(t, m2);
        // pixel 2q+1
        float n0 = vmax3(a0.y, a1y, a2.y);
        float n1 = vmax3(b0.y, b1y, b2.y);
        float n2 = vmax3(c0.y, c1y, c2.y);
        float u  = vmax3(acc[2 * q + 1], n0, n1);
        acc[2 * q + 1] = fmaxf(u, n2);
    }
}

// R13 skeleton (verified 57.3 us): wave computes TWO output rows from FOUR
// staged rows; block = (b, row-pair, half-row of 32 cols) = 512 thr = 8 waves
// = (px-quad x ci-half); LDS [ci][4 rows][40] = 40 KB; 512 blocks = 2/CU.
// Only change: packed-add core (-21% VALU instrs), single-ci loop body to
// stay far below the 128-VGPR cap (R11's double-ci pk version spilled).
__global__ __launch_bounds__(512, 4)
void maxconv_main(const float* __restrict__ x, const float* __restrict__ wT,
                  float* __restrict__ out) {
    __shared__ __align__(16) float xs[Ci * 160];   // 40960 B

    const int tid  = threadIdx.x;
    const int lane = tid & 63;
    const int wid  = tid >> 6;                      // 0..7

    // XCD chunking: 512 blocks, 64 per XCD = exactly one batch image b.
    const int lg   = ((blockIdx.x & 7) << 6) | (blockIdx.x >> 3);
    const int b    = lg >> 6;
    const int rem  = lg & 63;
    const int pair = rem >> 1;
    const int half = rem & 1;
    const int h0   = pair * 2;
    const int w0h  = half << 5;                     // 0 or 32

    // ---- upfront staging: 544 units = (4 ci-quarters) x (4 rows x 34 slots);
    // unit stages 16 ci of one (row,slot). Invalid coords write NEGV.
    for (int u = tid; u < 544; u += 512) {
        const int ciq  = u / 136;
        const int r2   = u - ciq * 136;
        const int r    = r2 / 34;
        const int s    = r2 - r * 34;
        const int cibase = ciq * 16;
        const int grow = h0 - 1 + r;
        const int gcol = w0h - 1 + s;
        const bool valid = (grow >= 0) && (grow < Hn) && (gcol >= 0) && (gcol < Wn);
        const int cg   = valid ? grow : 0;
        const int cc   = valid ? gcol : 0;
        const float* gp = x + (((size_t)b * Ci + cibase) * Hn + cg) * Wn + cc;
        const int dst  = r * 40 + s;
#pragma unroll 1
        for (int c8 = 0; c8 < 16; c8 += 8) {
            float v[8];
#pragma unroll
            for (int i = 0; i < 8; i++)
                v[i] = valid ? gp[(size_t)(c8 + i) * HW] : NEGV;
#pragma unroll
            for (int i = 0; i < 8; i++)
                xs[(cibase + c8 + i) * 160 + dst] = v[i];
        }
    }
    __syncthreads();

    const int quad   = wid >> 1;        // px-quad 0..3 (8 cols each)
    const int cihalf = wid & 1;         // 0: ci 0..31, 1: ci 32..63
    const int woff   = quad * 8;        // slot base (16B-aligned)

    const float* wq = wT + (size_t)cihalf * 32 * 576 + lane;
    const float* xq = xs + cihalf * 32 * 160 + woff;

    float acc0[8], acc1[8];
#pragma unroll
    for (int j = 0; j < 8; j++) { acc0[j] = NEGV; acc1[j] = NEGV; }

#pragma unroll 1
    for (int ci = 0; ci < 32; ci++) {
        float wv[9];
#pragma unroll
        for (int k = 0; k < 9; k++) wv[k] = wq[k * 64];   // coalesced, imm offs
        // splat pairs for the pk-able weight columns (left/right of each row)
        v2f ws0[6], ws1[6];
        ws0[0] = (v2f){wv[0], wv[0]}; ws0[1] = (v2f){wv[2], wv[2]};
        ws0[2] = (v2f){wv[3], wv[3]}; ws0[3] = (v2f){wv[5], wv[5]};
        ws0[4] = (v2f){wv[6], wv[6]}; ws0[5] = (v2f){wv[8], wv[8]};
        // identical set for the second out-row (same ci weights)
        ws1[0] = ws0[0]; ws1[1] = ws0[1]; ws1[2] = ws0[2];
        ws1[3] = ws0[3]; ws1[4] = ws0[4]; ws1[5] = ws0[5];

        v2f r0[5], r1[5], r2[5], r3[5];
        read10v(r0, xq);       read10v(r1, xq + 40);
        read10v(r2, xq + 80);  read10v(r3, xq + 120);
        compute8pk(acc0, r0, r1, r2, wv, ws0);   // out-row h0
        compute8pk(acc1, r1, r2, r3, wv, ws1);   // out-row h0+1
        wq += 576; xq += 160;
    }

    // ---- combine ci-halves via xs (dead after loop): half-1 parks, half-0
    // maxes and stores both rows.
    __syncthreads();
    if (cihalf) {
        float* ps = xs + quad * 1024 + lane * 16;
        *reinterpret_cast<float4*>(ps)      = make_float4(acc0[0], acc0[1], acc0[2], acc0[3]);
        *reinterpret_cast<float4*>(ps + 4)  = make_float4(acc0[4], acc0[5], acc0[6], acc0[7]);
        *reinterpret_cast<float4*>(ps + 8)  = make_float4(acc1[0], acc1[1], acc1[2], acc1[3]);
        *reinterpret_cast<float4*>(ps + 12) = make_float4(acc1[4], acc1[5], acc1[6], acc1[7]);
    }
    __syncthreads();
    if (!cihalf) {
        const float* ps = xs + quad * 1024 + lane * 16;
        float4 o0 = *reinterpret_cast<const float4*>(ps);
        float4 o1 = *reinterpret_cast<const float4*>(ps + 4);
        float4 o2 = *reinterpret_cast<const float4*>(ps + 8);
        float4 o3 = *reinterpret_cast<const float4*>(ps + 12);
        acc0[0] = fmaxf(acc0[0], o0.x); acc0[1] = fmaxf(acc0[1], o0.y);
        acc0[2] = fmaxf(acc0[2], o0.z); acc0[3] = fmaxf(acc0[3], o0.w);
        acc0[4] = fmaxf(acc0[4], o1.x); acc0[5] = fmaxf(acc0[5], o1.y);
        acc0[6] = fmaxf(acc0[6], o1.z); acc0[7] = fmaxf(acc0[7], o1.w);
        acc1[0] = fmaxf(acc1[0], o2.x); acc1[1] = fmaxf(acc1[1], o2.y);
        acc1[2] = fmaxf(acc1[2], o2.z); acc1[3] = fmaxf(acc1[3], o2.w);
        acc1[4] = fmaxf(acc1[4], o3.x); acc1[5] = fmaxf(acc1[5], o3.y);
        acc1[6] = fmaxf(acc1[6], o3.z); acc1[7] = fmaxf(acc1[7], o3.w);

        float* po = out + (((size_t)b * Co + lane) * Hn + h0) * Wn + w0h + woff;
        *reinterpret_cast<float4*>(po)          = make_float4(acc0[0], acc0[1], acc0[2], acc0[3]);
        *reinterpret_cast<float4*>(po + 4)      = make_float4(acc0[4], acc0[5], acc0[6], acc0[7]);
        *reinterpret_cast<float4*>(po + Wn)     = make_float4(acc1[0], acc1[1], acc1[2], acc1[3]);
        *reinterpret_cast<float4*>(po + Wn + 4) = make_float4(acc1[4], acc1[5], acc1[6], acc1[7]);
    }
}

extern "C" void kernel_launch(void* const* d_in, const int* in_sizes, int n_in,
                              void* d_out, int out_size, void* d_ws, size_t ws_size,
                              hipStream_t stream) {
    const float* x  = (const float*)d_in[0];
    const float* wt = (const float*)d_in[1];
    float* out = (float*)d_out;
    float* wT  = (float*)d_ws;   // 147456 B

    wtrans_kernel<<<(WT_ELEMS + 255) / 256, 256, 0, stream>>>(wt, wT);

    // 512 blocks x 512 threads = 2 blocks/CU = 16 waves/CU; LDS 40 KB x 2.
    maxconv_main<<<512, 512, 0, stream>>>(x, wT, out);
}